// Round 9
// baseline (405.910 us; speedup 1.0000x reference)
//
#include <hip/hip_runtime.h>
#include <stdint.h>

typedef unsigned short u16;
typedef short bf16x8 __attribute__((ext_vector_type(8)));
typedef float f32x4 __attribute__((ext_vector_type(4)));

#define TOKENS 8192
#define SEQ 2048
#define DM 1024
#define DI 2048
#define NCH 32   // time chunks per sequence
#define CLEN 64  // SEQ / NCH

__device__ __forceinline__ float bf2f(u16 u) {
  union { uint32_t i; float f; } v; v.i = ((uint32_t)u) << 16; return v.f;
}
__device__ __forceinline__ u16 f2bf(float f) {
  union { float f; uint32_t i; } v; v.f = f;
  uint32_t r = v.i + 0x7FFFu + ((v.i >> 16) & 1u);
  return (u16)(r >> 16);
}

__device__ __forceinline__ void g2lds16(const void* g, void* l) {
  __builtin_amdgcn_global_load_lds(
      (const __attribute__((address_space(1))) uint32_t*)g,
      (__attribute__((address_space(3))) uint32_t*)l, 16, 0, 0);
}

// ---------------- transpose fp32 [R][C] -> bf16 [C][R] ----------------
__global__ __launch_bounds__(256)
void transpose_to_bf16(const float* __restrict__ src, u16* __restrict__ dst,
                       int R, int C) {
  __shared__ float tile[64][65];
  const int i = threadIdx.x;
  const int tilesC = C >> 6;
  const int br = blockIdx.x / tilesC, bc = blockIdx.x % tilesC;
  const int r0 = br << 6, c0 = bc << 6;
  const int cx = (i & 15) << 2, ry = i >> 4;
#pragma unroll
  for (int p = 0; p < 4; ++p) {
    int row = ry + p * 16;
    float4 v = *(const float4*)&src[(size_t)(r0 + row) * C + c0 + cx];
    tile[row][cx + 0] = v.x; tile[row][cx + 1] = v.y;
    tile[row][cx + 2] = v.z; tile[row][cx + 3] = v.w;
  }
  __syncthreads();
#pragma unroll
  for (int p = 0; p < 4; ++p) {
    int cr = ry + p * 16;  // output row = source col c0+cr
    ushort4 o;
    o.x = f2bf(tile[cx + 0][cr]); o.y = f2bf(tile[cx + 1][cr]);
    o.z = f2bf(tile[cx + 2][cr]); o.w = f2bf(tile[cx + 3][cr]);
    *(ushort4*)&dst[(size_t)(c0 + cr) * R + r0 + cx] = o;
  }
}

// ---------------- transpose W_x fp32 [2048][32] -> bf16 [32][2048] ----------------
__global__ __launch_bounds__(256)
void txpose_wx(const float* __restrict__ src, u16* __restrict__ dst) {
  const int gid = blockIdx.x * 256 + threadIdx.x;  // 65536
  const int k = gid >> 5, n = gid & 31;
  dst[(size_t)n * DI + k] = f2bf(src[gid]);
}

// ---------------- layernorm fp32 -> bf16 ----------------
__global__ __launch_bounds__(256)
void layernorm_bf16(const float* __restrict__ x, const float* __restrict__ lw,
                    const float* __restrict__ lb, u16* __restrict__ xn) {
  const int row = blockIdx.x, tid = threadIdx.x;
  const float4 v = *(const float4*)&x[(size_t)row * DM + tid * 4];
  float s = v.x + v.y + v.z + v.w;
  float q = v.x * v.x + v.y * v.y + v.z * v.z + v.w * v.w;
#pragma unroll
  for (int m = 1; m < 64; m <<= 1) { s += __shfl_xor(s, m); q += __shfl_xor(q, m); }
  __shared__ float red[8];
  const int w = tid >> 6, lane = tid & 63;
  if (lane == 0) { red[w] = s; red[4 + w] = q; }
  __syncthreads();
  s = red[0] + red[1] + red[2] + red[3];
  q = red[4] + red[5] + red[6] + red[7];
  const float mu = s * (1.f / DM);
  const float var = q * (1.f / DM) - mu * mu;
  const float rs = rsqrtf(var + 1e-5f);
  const float4 wv = *(const float4*)&lw[tid * 4];
  const float4 bv = *(const float4*)&lb[tid * 4];
  ushort4 o;
  o.x = f2bf((v.x - mu) * rs * wv.x + bv.x);
  o.y = f2bf((v.y - mu) * rs * wv.y + bv.y);
  o.z = f2bf((v.z - mu) * rs * wv.z + bv.z);
  o.w = f2bf((v.w - mu) * rs * wv.w + bv.w);
  *(ushort4*)&xn[(size_t)row * DM + tid * 4] = o;
}

// ---------------- 8-phase 256x256 MFMA GEMM (per-wave 128x64) ----------------
// BM=BN=256, BK=64; 8 waves (2Mx4N); 2-buffer LDS (128 KB); 4 quadrant-phases
// per K-tile; counted vmcnt(6) once per K-tile (never 0 in steady state).
// Stage ledger per tile t phase q (unit = 64 rows = one g2lds across 512 thr):
//   q0: A1,A3 of t+1; q1: B0,B1 of t+2; q2: B2,B3 of t+2; q3: A0,A2 of t+2.
// vmcnt(6)@q3 => tile t+1 resident. LDS slot: A [0,32768)B, B [32768,65536)B.
// KSPL>1: grid = mnTiles*KSPL; each split computes K/KSPL; EPI==2 stores bf16
// partials (no bias) at out + ksp*M*N.
#define TILE256 (2 * 256 * 64)  // u16 per dbuf slot (A 256x64 + B 256x64)
template <int EPI, int KSPL>
__global__ __launch_bounds__(512, 2)
void gemm8(const u16* __restrict__ A, const u16* __restrict__ Bt,
           const float* __restrict__ bias, u16* __restrict__ out,
           int M, int N, int K) {
  __shared__ __align__(16) u16 lds[2 * TILE256];  // 128 KB
  const int tid = threadIdx.x, wid = tid >> 6, lane = tid & 63;
  const int ntiles = N >> 8;
  int bid = blockIdx.x;
  {  // XCD-aware swizzle (grid % 8 == 0)
    const int cpx = gridDim.x >> 3;
    bid = (bid & 7) * cpx + (bid >> 3);
  }
  const int mnt = (M >> 8) * ntiles;
  const int ksp = (KSPL > 1) ? (bid / mnt) : 0;
  const int mnb = (KSPL > 1) ? (bid % mnt) : bid;
  const int klen = K / KSPL;
  const int kbase = ksp * klen;
  const int tm = mnb / ntiles, tn = mnb % ntiles;
  const int m0 = tm << 8, n0 = tn << 8;
  const int wm = (wid >> 2) * 128, wn = (wid & 3) * 64;
  const int fr = lane & 15, fg = lane >> 4;
  const int c0 = (fg ^ (fr & 7)) << 4;  // swizzled byte offset of ks0 chunk
  const int NK = klen >> 6;

  f32x4 acc[8][4];
#pragma unroll
  for (int mi = 0; mi < 8; ++mi)
#pragma unroll
    for (int ni = 0; ni < 4; ++ni) acc[mi][ni] = (f32x4){0.f, 0.f, 0.f, 0.f};

  // stage one 64-row unit (8 KB) of tile T, matrix isB, unit u
  auto stage_unit = [&](int T, int isB, int u) {
    const int kt = T << 6;
    const int row = u * 64 + (tid >> 3);
    const int l = (tid & 7) ^ (row & 7);
    const u16* src = (isB ? Bt + (size_t)(n0 + row) * K
                          : A + (size_t)(m0 + row) * K) + kbase + kt + l * 8;
    g2lds16(src, lds + (size_t)(T & 1) * TILE256 + isB * 16384 + u * 4096 + tid * 8);
  };

  // prologue: tile0 full (8), tile1 B0-3 + A0,A2 (6) -> vmcnt(6) = tile0 landed
#pragma unroll
  for (int u = 0; u < 4; ++u) stage_unit(0, 1, u);
#pragma unroll
  for (int u = 0; u < 4; ++u) stage_unit(0, 0, u);
#pragma unroll
  for (int u = 0; u < 4; ++u) stage_unit(1, 1, u);
  stage_unit(1, 0, 0); stage_unit(1, 0, 2);
  asm volatile("s_waitcnt vmcnt(6)" ::: "memory");
  __builtin_amdgcn_s_barrier();
  asm volatile("" ::: "memory");

  bf16x8 bfr[2][4];
  for (int t = 0; t < NK; ++t) {
    const char* bufA = (const char*)(lds + (t & 1) * TILE256);
    const char* bufB = bufA + 32768;  // A region is 256*64*2 = 32768 bytes
#pragma unroll
    for (int q = 0; q < 4; ++q) {
      // ---- ds_read register subtile ----
      bf16x8 af[2][2];
      if (q == 0) {
#pragma unroll
        for (int ks = 0; ks < 2; ++ks) {
          const int cb = c0 ^ (ks << 6);
#pragma unroll
          for (int ni = 0; ni < 4; ++ni)
            bfr[ks][ni] = *(const bf16x8*)(bufB + (wn + ni * 16 + fr) * 128 + cb);
        }
      }
#pragma unroll
      for (int ks = 0; ks < 2; ++ks) {
        const int cb = c0 ^ (ks << 6);
#pragma unroll
        for (int r = 0; r < 2; ++r)
          af[ks][r] = *(const bf16x8*)(bufA + (wm + (2 * q + r) * 16 + fr) * 128 + cb);
      }
      // ---- stage per ledger ----
      if (q == 0) {
        if (t + 1 < NK) { stage_unit(t + 1, 0, 1); stage_unit(t + 1, 0, 3); }
      } else if (q == 1) {
        if (t + 2 < NK) { stage_unit(t + 2, 1, 0); stage_unit(t + 2, 1, 1); }
      } else if (q == 2) {
        if (t + 2 < NK) { stage_unit(t + 2, 1, 2); stage_unit(t + 2, 1, 3); }
      } else {
        if (t + 2 < NK) { stage_unit(t + 2, 0, 0); stage_unit(t + 2, 0, 2); }
      }
      __builtin_amdgcn_sched_barrier(0);
      __builtin_amdgcn_s_barrier();
      asm volatile("s_waitcnt lgkmcnt(0)" ::: "memory");
      __builtin_amdgcn_sched_barrier(0);
      __builtin_amdgcn_s_setprio(1);
#pragma unroll
      for (int ks = 0; ks < 2; ++ks)
#pragma unroll
        for (int r = 0; r < 2; ++r)
#pragma unroll
          for (int ni = 0; ni < 4; ++ni)
            acc[2 * q + r][ni] = __builtin_amdgcn_mfma_f32_16x16x32_bf16(
                af[ks][r], bfr[ks][ni], acc[2 * q + r][ni], 0, 0, 0);
      __builtin_amdgcn_s_setprio(0);
      if (q == 3) {
        if (t + 2 < NK) {
          asm volatile("s_waitcnt vmcnt(6)" ::: "memory");
        } else if (t + 1 < NK) {
          asm volatile("s_waitcnt vmcnt(0)" ::: "memory");
        }
      }
      __builtin_amdgcn_s_barrier();
      asm volatile("" ::: "memory");
    }
  }

  u16* outp = out + (size_t)ksp * M * N;
#pragma unroll
  for (int mi = 0; mi < 8; ++mi)
#pragma unroll
    for (int ni = 0; ni < 4; ++ni) {
      const int col = n0 + wn + ni * 16 + fr;
      const float bcol = (EPI == 0) ? bias[col] : 0.f;
#pragma unroll
      for (int j = 0; j < 4; ++j) {
        const int row = m0 + wm + mi * 16 + fg * 4 + j;
        outp[(size_t)row * N + col] = f2bf(acc[mi][ni][j] + bcol);
      }
    }
}

// ---------------- reduce split-K bf16 partials + bias + residual -> fp32 ------
__global__ __launch_bounds__(256)
void out_reduce(const u16* __restrict__ part, const float* __restrict__ x,
                const float* __restrict__ bias, float* __restrict__ out) {
  const int total4 = TOKENS * DM / 4;
  for (int b4 = blockIdx.x * 256 + threadIdx.x; b4 < total4; b4 += gridDim.x * 256) {
    const int i4 = b4 * 4;
    const int c = i4 & (DM - 1);
    const float4 xv = *(const float4*)&x[i4];
    const float4 bv = *(const float4*)&bias[c];
    float s0 = 0.f, s1 = 0.f, s2 = 0.f, s3 = 0.f;
#pragma unroll
    for (int sp = 0; sp < 4; ++sp) {
      const ushort4 p = *(const ushort4*)&part[(size_t)sp * TOKENS * DM + i4];
      s0 += bf2f(p.x); s1 += bf2f(p.y); s2 += bf2f(p.z); s3 += bf2f(p.w);
    }
    float4 o;
    o.x = s0 + xv.x + bv.x; o.y = s1 + xv.y + bv.y;
    o.z = s2 + xv.z + bv.z; o.w = s3 + xv.w + bv.w;
    *(float4*)&out[i4] = o;
  }
}

// ---------------- causal conv1d + SiLU (elementwise) ----------------
__global__ __launch_bounds__(256)
void conv_silu(const u16* __restrict__ xg, const float* __restrict__ cw,
               const float* __restrict__ cb, u16* __restrict__ xconv) {
  const int t = blockIdx.x;
  const int s = t & (SEQ - 1);
  const int d = threadIdx.x * 8;
  float xv[4][8];
#pragma unroll
  for (int j = 0; j < 4; ++j) {
    const int ss = s - 3 + j;
    if (ss >= 0) {
      uint4 u = *(const uint4*)&xg[(size_t)(t - 3 + j) * (2 * DI) + d];
      const u16* pu = (const u16*)&u;
#pragma unroll
      for (int q = 0; q < 8; ++q) xv[j][q] = bf2f(pu[q]);
    } else {
#pragma unroll
      for (int q = 0; q < 8; ++q) xv[j][q] = 0.f;
    }
  }
  u16 outp[8];
#pragma unroll
  for (int q = 0; q < 8; ++q) {
    const float4 wq = *(const float4*)&cw[(d + q) * 4];
    float a = cb[d + q] + wq.x * xv[0][q] + wq.y * xv[1][q] + wq.z * xv[2][q] +
              wq.w * xv[3][q];
    outp[q] = f2bf(a / (1.f + __expf(-a)));
  }
  *(uint4*)&xconv[(size_t)t * DI + d] = *(const uint4*)outp;
}

// ---------------- BC projection: split-K MFMA GEMM ----------------
__global__ __launch_bounds__(256)
void bc_gemm(const u16* __restrict__ xconv, const u16* __restrict__ wxT,
             float* __restrict__ BCp) {
  __shared__ __align__(16) u16 As[128 * 64];
  __shared__ __align__(16) u16 Bs[32 * 64];
  const int tid = threadIdx.x, w = tid >> 6, lane = tid & 63;
  const int mt = blockIdx.x & 63;
  const int ks_id = blockIdx.x >> 6;
  const int m0 = mt << 7;
  const int k0 = ks_id << 9;
  const int fr = lane & 15, fg = lane >> 4;
  f32x4 acc[2][2];
#pragma unroll
  for (int mf = 0; mf < 2; ++mf)
#pragma unroll
    for (int nf = 0; nf < 2; ++nf) acc[mf][nf] = (f32x4){0.f, 0.f, 0.f, 0.f};

  for (int kt = k0; kt < k0 + 512; kt += 64) {
#pragma unroll
    for (int i = 0; i < 4; ++i) {
      int ch = w * 64 + lane + i * 256;
      int row = ch >> 3, c16 = ch & 7;
      g2lds16(xconv + (size_t)(m0 + row) * DI + kt + c16 * 8,
              (u16*)As + (size_t)(w * 64 + i * 256) * 8);
    }
    {
      int row = tid >> 3, c16 = tid & 7;
      g2lds16(wxT + (size_t)row * DI + kt + c16 * 8,
              (u16*)Bs + (size_t)(w * 64) * 8);
    }
    __syncthreads();
#pragma unroll
    for (int ks = 0; ks < 2; ++ks) {
      bf16x8 af[2], bfr[2];
#pragma unroll
      for (int mf = 0; mf < 2; ++mf)
        af[mf] = *(const bf16x8*)&As[(w * 32 + mf * 16 + fr) * 64 + ks * 32 + fg * 8];
#pragma unroll
      for (int nf = 0; nf < 2; ++nf)
        bfr[nf] = *(const bf16x8*)&Bs[(nf * 16 + fr) * 64 + ks * 32 + fg * 8];
#pragma unroll
      for (int mf = 0; mf < 2; ++mf)
#pragma unroll
        for (int nf = 0; nf < 2; ++nf)
          acc[mf][nf] = __builtin_amdgcn_mfma_f32_16x16x32_bf16(
              af[mf], bfr[nf], acc[mf][nf], 0, 0, 0);
    }
    __syncthreads();
  }
#pragma unroll
  for (int mf = 0; mf < 2; ++mf)
#pragma unroll
    for (int nf = 0; nf < 2; ++nf) {
      const int col = nf * 16 + fr;
#pragma unroll
      for (int j = 0; j < 4; ++j) {
        const int row = m0 + w * 32 + mf * 16 + fg * 4 + j;
        BCp[((size_t)ks_id * TOKENS + row) * 32 + col] = acc[mf][nf][j];
      }
    }
}

// ---------------- reduce split-K partials + bias (plane layout) --------------
// BC[t][0..16) = B-plane, BC[t][16..32) = C-plane
__global__ __launch_bounds__(256)
void bc_reduce(const float* __restrict__ BCp, const float* __restrict__ bx,
               float* __restrict__ BC) {
  const int gid = blockIdx.x * 256 + threadIdx.x;
  const int c = gid & 31;
  const size_t t = gid >> 5;
  float s = bx[c] + BCp[t * 32 + c] + BCp[((size_t)TOKENS + t) * 32 + c] +
            BCp[((size_t)2 * TOKENS + t) * 32 + c] +
            BCp[((size_t)3 * TOKENS + t) * 32 + c];
  BC[t * 32 + c] = s;
}

// ---------------- chunked selective scan ----------------
__global__ __launch_bounds__(256)
void scan_passA(const u16* __restrict__ xconv, const float* __restrict__ BC,
                const float* __restrict__ A_log, float* __restrict__ F) {
  __shared__ float bcs[CLEN * 32];
  const int blk = blockIdx.x;
  const int j = blk & (NCH - 1);
  const int dg = (blk >> 5) & 7;
  const int b = blk >> 8;
  const int tid = threadIdx.x;
  const int d = dg * 256 + tid;
  const int t0 = j * CLEN;
  {
    const float4* s4 = (const float4*)(BC + (size_t)(b * SEQ + t0) * 32);
    float4* d4 = (float4*)bcs;
#pragma unroll
    for (int i = 0; i < 2; ++i) d4[tid + i * 256] = s4[tid + i * 256];
  }
  float dA[16], h[16];
#pragma unroll
  for (int n = 0; n < 16; ++n) {
    dA[n] = __expf(-__expf(A_log[d * 16 + n]));
    h[n] = 0.f;
  }
  __syncthreads();
  const u16* xcp = xconv + (size_t)(b * SEQ + t0) * DI + d;
#pragma unroll 2
  for (int t = 0; t < CLEN; ++t) {
    const float xc = bf2f(*xcp);
    xcp += DI;
    const float* bt = &bcs[t * 32];
#pragma unroll
    for (int n4 = 0; n4 < 4; ++n4) {
      const float4 bv = *(const float4*)&bt[n4 * 4];
      h[4 * n4 + 0] = fmaf(dA[4 * n4 + 0], h[4 * n4 + 0], xc * bv.x);
      h[4 * n4 + 1] = fmaf(dA[4 * n4 + 1], h[4 * n4 + 1], xc * bv.y);
      h[4 * n4 + 2] = fmaf(dA[4 * n4 + 2], h[4 * n4 + 2], xc * bv.z);
      h[4 * n4 + 3] = fmaf(dA[4 * n4 + 3], h[4 * n4 + 3], xc * bv.w);
    }
  }
  float* fp = F + ((size_t)((b * NCH + j) * DI) + d) * 16;
#pragma unroll
  for (int n = 0; n < 16; n += 4) {
    float4 v = {h[n], h[n + 1], h[n + 2], h[n + 3]};
    *(float4*)&fp[n] = v;
  }
}

__global__ __launch_bounds__(256)
void scan_passB(const float* __restrict__ A_log, float* __restrict__ F) {
  const int gid = blockIdx.x * 256 + threadIdx.x;
  const int n = gid & 15;
  const int d = (gid >> 4) & (DI - 1);
  const int b = gid >> 15;
  const float dAL = __expf(-(float)CLEN * __expf(A_log[d * 16 + n]));
  float carry = 0.f;
  const size_t base = ((size_t)(b * NCH) * DI + d) * 16 + n;
  const size_t stride = (size_t)DI * 16;
  for (int j = 0; j < NCH; ++j) {
    const size_t idx = base + (size_t)j * stride;
    const float f = F[idx];
    F[idx] = carry;
    carry = fmaf(dAL, carry, f);
  }
}

__global__ __launch_bounds__(256)
void scan_passC(const u16* __restrict__ xconv, const u16* __restrict__ xg,
                const float* __restrict__ BC, const float* __restrict__ A_log,
                const float* __restrict__ Dv, const float* __restrict__ F,
                u16* __restrict__ yact) {
  __shared__ float bcs[CLEN * 32];
  const int blk = blockIdx.x;
  const int j = blk & (NCH - 1);
  const int dg = (blk >> 5) & 7;
  const int b = blk >> 8;
  const int tid = threadIdx.x;
  const int d = dg * 256 + tid;
  const int t0 = j * CLEN;
  {
    const float4* s4 = (const float4*)(BC + (size_t)(b * SEQ + t0) * 32);
    float4* d4 = (float4*)bcs;
#pragma unroll
    for (int i = 0; i < 2; ++i) d4[tid + i * 256] = s4[tid + i * 256];
  }
  float dA[16], h[16];
  const float* fp = F + ((size_t)((b * NCH + j) * DI) + d) * 16;
#pragma unroll
  for (int n = 0; n < 16; n += 4) {
    float4 v = *(const float4*)&fp[n];
    h[n] = v.x; h[n + 1] = v.y; h[n + 2] = v.z; h[n + 3] = v.w;
  }
#pragma unroll
  for (int n = 0; n < 16; ++n) dA[n] = __expf(-__expf(A_log[d * 16 + n]));
  const float Dd = Dv[d];
  __syncthreads();
  const u16* xcp = xconv + (size_t)(b * SEQ + t0) * DI + d;
  const u16* gp = xg + (size_t)(b * SEQ + t0) * (2 * DI) + DI + d;
  u16* yp = yact + (size_t)(b * SEQ + t0) * DI + d;
#pragma unroll 2
  for (int t = 0; t < CLEN; ++t) {
    const float xc = bf2f(*xcp);
    const float g = bf2f(*gp);
    const float* bt = &bcs[t * 32];
    float y0 = 0.f, y1 = 0.f, y2 = 0.f, y3 = 0.f;
#pragma unroll
    for (int n4 = 0; n4 < 4; ++n4) {
      const float4 bv = *(const float4*)&bt[n4 * 4];
      const float4 cv = *(const float4*)&bt[16 + n4 * 4];
      const int n = 4 * n4;
      h[n]     = fmaf(dA[n],     h[n],     xc * bv.x);
      y0 = fmaf(cv.x, h[n], y0);
      h[n + 1] = fmaf(dA[n + 1], h[n + 1], xc * bv.y);
      y1 = fmaf(cv.y, h[n + 1], y1);
      h[n + 2] = fmaf(dA[n + 2], h[n + 2], xc * bv.z);
      y2 = fmaf(cv.z, h[n + 2], y2);
      h[n + 3] = fmaf(dA[n + 3], h[n + 3], xc * bv.w);
      y3 = fmaf(cv.w, h[n + 3], y3);
    }
    const float y = (y0 + y1) + (y2 + y3);
    const float ya = (y + xc * Dd) * (g / (1.f + __expf(-g)));
    *yp = f2bf(ya);
    xcp += DI; gp += 2 * DI; yp += DI;
  }
}

extern "C" void kernel_launch(void* const* d_in, const int* in_sizes, int n_in,
                              void* d_out, int out_size, void* d_ws, size_t ws_size,
                              hipStream_t stream) {
  const float* x     = (const float*)d_in[0];
  const float* ln_w  = (const float*)d_in[1];
  const float* ln_b  = (const float*)d_in[2];
  const float* W_in  = (const float*)d_in[3];
  const float* b_in  = (const float*)d_in[4];
  const float* cw    = (const float*)d_in[5];
  const float* cb    = (const float*)d_in[6];
  const float* A_log = (const float*)d_in[7];
  const float* Dv    = (const float*)d_in[8];
  const float* W_x   = (const float*)d_in[9];
  const float* b_x   = (const float*)d_in[10];
  const float* W_out = (const float*)d_in[11];
  const float* b_out = (const float*)d_in[12];

  char* ws = (char*)d_ws;
  size_t off = 0;
  auto alloc = [&](size_t bytes) {
    void* p = ws + off;
    off += (bytes + 255) & ~(size_t)255;
    return p;
  };
  u16* WinT  = (u16*)alloc((size_t)(2 * DI) * DM * 2);
  u16* WoutT = (u16*)alloc((size_t)DM * DI * 2);
  u16* xn    = (u16*)alloc((size_t)TOKENS * DM * 2);  // reused as F after GEMM1
  u16* xg    = (u16*)alloc((size_t)TOKENS * (2 * DI) * 2);  // reused as G2 partials
  u16* xconv = (u16*)alloc((size_t)TOKENS * DI * 2);
  float* BC  = (float*)alloc((size_t)TOKENS * 32 * 4);
  u16* yact  = (u16*)alloc((size_t)TOKENS * DI * 2);
  u16* WxT   = (u16*)alloc((size_t)32 * DI * 2);
  float* BCp = (float*)alloc((size_t)4 * TOKENS * 32 * 4);
  float* F   = (float*)xn;   // 16 MB, xn dead after GEMM1
  u16* Gpart = xg;           // 4*8192*1024*2 = 64 MB, xg dead after scanC
  (void)ws_size; (void)in_sizes; (void)n_in; (void)out_size;

  transpose_to_bf16<<<(DM / 64) * ((2 * DI) / 64), 256, 0, stream>>>(W_in, WinT, DM, 2 * DI);
  transpose_to_bf16<<<(DI / 64) * (DM / 64), 256, 0, stream>>>(W_out, WoutT, DI, DM);
  txpose_wx<<<(DI * 32) / 256, 256, 0, stream>>>(W_x, WxT);
  layernorm_bf16<<<TOKENS, 256, 0, stream>>>(x, ln_w, ln_b, xn);
  gemm8<0, 1><<<(TOKENS / 256) * ((2 * DI) / 256), 512, 0, stream>>>(
      xn, WinT, b_in, xg, TOKENS, 2 * DI, DM);
  conv_silu<<<TOKENS, 256, 0, stream>>>(xg, cw, cb, xconv);
  bc_gemm<<<256, 256, 0, stream>>>(xconv, WxT, BCp);
  bc_reduce<<<(TOKENS * 32) / 256, 256, 0, stream>>>(BCp, b_x, BC);
  scan_passA<<<4 * 8 * NCH, 256, 0, stream>>>(xconv, BC, A_log, F);
  scan_passB<<<512, 256, 0, stream>>>(A_log, F);
  scan_passC<<<4 * 8 * NCH, 256, 0, stream>>>(xconv, xg, BC, A_log, Dv, F, yact);
  // GEMM2: split-K=4 over K=2048 (8 K-tiles each), 512 blocks (2/CU), bf16 partials
  gemm8<2, 4><<<(TOKENS / 256) * (DM / 256) * 4, 512, 0, stream>>>(
      yact, WoutT, nullptr, Gpart, TOKENS, DM, DI);
  out_reduce<<<2048, 256, 0, stream>>>(Gpart, x, b_out, (float*)d_out);
}